// Round 5
// baseline (134.921 us; speedup 1.0000x reference)
//
#include <hip/hip_runtime.h>
#include <math.h>

#define NG 256
#define NG3 (NG*NG*NG)
#define NW (NG3/64)          // 262144 u64 words, z-packed

typedef unsigned long long u64;
typedef unsigned int u32;
typedef unsigned short u16;

constexpr float SPACING_F = 0.390625f;   // 100/256, exact
constexpr int KH = 8;
constexpr int KD = 17;

#define NBIN 64              // xy bins per axis, 4 voxels each
#define BCAP 32              // atoms per bin cap (mean 1.22)
#define NCAND 160            // candidates per block cap (mean ~78)
#define QCAP 8192            // (atom,col) pairs per block cap (mean ~3633)

// word layout: word = ((x<<8|y)<<2)|wz ; bit i = voxel z = wz*64+i
#define CB(x, y) (((((x) & 255) << 8) | ((y) & 255)) << 2)

// ---------------- Stage 0: bin atoms by xy ---------------------------------
__global__ void bin_fill_kernel(const float* __restrict__ xyz, int natoms,
                                int* __restrict__ bin_cnt, int* __restrict__ bin_list)
{
    int a = blockIdx.x * 256 + threadIdx.x;
    if (a >= natoms) return;
    float ax = xyz[a * 3 + 0], ay = xyz[a * 3 + 1];
    int bx = (int)floorf(__fdiv_rn(ax, SPACING_F));
    int by = (int)floorf(__fdiv_rn(ay, SPACING_F));
    int b = ((by >> 2) & (NBIN - 1)) * NBIN + ((bx >> 2) & (NBIN - 1));
    int s = atomicAdd(&bin_cnt[b], 1);
    if (s < BCAP) bin_list[b * BCAP + s] = a;
}

// ---------------- Stage 1: gather splat, no global atomics -----------------
// Block = 16x16 columns. LDS tiles in u32 halves, layout [lx][ly][wz][h].
__global__ void __launch_bounds__(256) gather_splat_kernel(
    const float* __restrict__ xyz, const float* __restrict__ vdw,
    const int* __restrict__ bin_cnt, const int* __restrict__ bin_list,
    u64* __restrict__ occ_bits, u64* __restrict__ p_bits)
{
    __shared__ float4 candF[NCAND];          // ax, ay, az, vr
    __shared__ int4   candI[NCAND];          // bx, by, bz, -
    __shared__ u32 occT[2048];               // 16*16 cols * 8 u32 (256 bits)
    __shared__ u32 pT[2048];
    __shared__ u16 queue[QCAP];
    __shared__ int lc, qn;

    const int tid = threadIdx.x;
    const int BX = blockIdx.x & 15, BY = blockIdx.x >> 4;
    const int x0 = BX * 16, y0 = BY * 16;
    const int lx = tid & 15, ly = tid >> 4;
    const int X = x0 + lx, Y = y0 + ly;
    const int lane = tid & 63;

    if (tid == 0) { lc = 0; qn = 0; }
    #pragma unroll
    for (int k = 0; k < 8; ++k) { occT[tid + k * 256] = 0; pT[tid + k * 256] = 0; }
    __syncthreads();

    // ---- build candidate list from the 8x8 bin window ----
    if (tid < 64) {
        int abx = (4 * BX - 2 + (tid & 7)) & (NBIN - 1);
        int aby = (4 * BY - 2 + (tid >> 3)) & (NBIN - 1);
        int b = aby * NBIN + abx;
        int n = min(bin_cnt[b], BCAP);
        if (n > 0) {
            int base = atomicAdd(&lc, n);
            for (int j = 0; j < n; ++j) {
                int idx = base + j;
                if (idx < NCAND) {
                    int a = bin_list[b * BCAP + j];
                    float ax = xyz[a * 3 + 0], ay = xyz[a * 3 + 1], az = xyz[a * 3 + 2];
                    candF[idx] = make_float4(ax, ay, az, vdw[a]);
                    int bx = (int)floorf(__fdiv_rn(ax, SPACING_F));
                    int by = (int)floorf(__fdiv_rn(ay, SPACING_F));
                    int bz = (int)floorf(__fdiv_rn(az, SPACING_F));
                    candI[idx] = make_int4(bx, by, bz, 0);
                }
            }
        }
    }
    __syncthreads();
    const int nc = min(lc, NCAND);

    // ---- phase A: per-column disk test, wave-compact into queue ----
    for (int c = 0; c < nc; ++c) {
        float4 f = candF[c];
        int4 bi = candI[c];
        int dx = ((X - bi.x + 128) & 255) - 128;   // wrapped-nearest offset
        int dy = ((Y - bi.y + 128) & 255) - 128;
        bool pass = false;
        if (dx >= -KH && dx <= KH && dy >= -KH && dy <= KH) {
            float ex = __fsub_rn(__fmul_rn((float)(bi.x + dx), SPACING_F), f.x);
            float ey = __fsub_rn(__fmul_rn((float)(bi.y + dy), SPACING_F), f.y);
            float rxy2 = __fadd_rn(__fmul_rn(ex, ex), __fmul_rn(ey, ey));
            float br = __fadd_rn(f.w, 1.1f);
            pass = rxy2 < __fmul_rn(br, br);       // same early-out proof as scatter
        }
        u64 bal = __ballot(pass);
        if (bal) {
            int leader = __ffsll((long long)bal) - 1;
            int base = 0;
            if (lane == leader) base = atomicAdd(&qn, __popcll(bal));
            base = __shfl(base, leader, 64);
            if (pass) {
                int r = __popcll(bal & ((1ull << lane) - 1ull));
                int q = base + r;
                if (q < QCAP) queue[q] = (u16)((c << 8) | tid);
            }
        }
    }
    __syncthreads();
    const int nq = min(qn, QCAP);

    // ---- phase B: dense 17-z loops, deposit via LDS 32-bit atomicOr ----
    for (int q = tid; q < nq; q += 256) {
        u16 e = queue[q];
        int c = e >> 8, col = e & 255;
        float4 f = candF[c];
        int4 bi = candI[c];
        int clx = col & 15, cly = col >> 4;
        int dx = (((x0 + clx) - bi.x + 128) & 255) - 128;
        int dy = (((y0 + cly) - bi.y + 128) & 255) - 128;
        float ex = __fsub_rn(__fmul_rn((float)(bi.x + dx), SPACING_F), f.x);
        float ey = __fsub_rn(__fmul_rn((float)(bi.y + dy), SPACING_F), f.y);
        float rxy2 = __fadd_rn(__fmul_rn(ex, ex), __fmul_rn(ey, ey));
        float vr = f.w;
        float br = __fadd_rn(vr, 1.1f);
        u32 mo = 0, mp = 0;
        #pragma unroll
        for (int k = 0; k < KD; ++k) {
            int cz = bi.z + k - KH;
            float ez = __fsub_rn(__fmul_rn((float)cz, SPACING_F), f.z);
            float s = __fadd_rn(rxy2, __fmul_rn(ez, ez));   // same assoc as ref
            float d = __fsqrt_rn(s);
            mo |= (d < br) ? (1u << k) : 0u;
            mp |= (d < vr) ? (1u << k) : 0u;
        }
        if (!mo) continue;
        int zA = (bi.z - KH) & 255;           // z of mask bit 0 (wrapped)
        int base32 = clx * 128 + cly * 8;     // [lx][ly] column, 8 u32 of z-bits
        int w0 = zA >> 5, off = zA & 31;
        u64 m = (u64)mo << off;
        u32 lo = (u32)m, hi = (u32)(m >> 32);
        if (lo) atomicOr(&occT[base32 + w0], lo);
        if (hi) atomicOr(&occT[base32 + ((w0 + 1) & 7)], hi);
        if (mp) {
            u64 pm = (u64)mp << off;
            u32 plo = (u32)pm, phi = (u32)(pm >> 32);
            if (plo) atomicOr(&pT[base32 + w0], plo);
            if (phi) atomicOr(&pT[base32 + ((w0 + 1) & 7)], phi);
        }
    }
    __syncthreads();

    // ---- flush tiles: coalesced uint4 stores, whole region written ----
    u32* og = (u32*)occ_bits;
    u32* pg = (u32*)p_bits;
    #pragma unroll
    for (int k = 0; k < 2; ++k) {
        int i = tid * 4 + k * 1024;           // 0..2044, step 4
        int xx = i >> 7;                      // local x
        int rem = i & 127;                    // y_local*8 + wz*2 + h
        u32 gbase = ((u32)(x0 + xx) << 11) + ((u32)y0 << 3) + (u32)rem;
        *(uint4*)(og + gbase) = make_uint4(occT[i], occT[i+1], occT[i+2], occT[i+3]);
        *(uint4*)(pg + gbase) = make_uint4(pT[i], pT[i+1], pT[i+2], pT[i+3]);
    }
}

// ---------------- Stage 2: bit-parallel erosion -> solvent bits ------------
__device__ __forceinline__ u64 rng5(const u64* __restrict__ B, int cb, int wz) {
    u64 C = B[cb | wz], P = B[cb | ((wz + 3) & 3)], Nw = B[cb | ((wz + 1) & 3)];
    u64 d1 = (C << 1) | (P >> 63), d2 = (C << 2) | (P >> 62);
    u64 u1 = (C >> 1) | (Nw << 63), u2 = (C >> 2) | (Nw << 62);
    return C & d1 & d2 & u1 & u2;
}
__device__ __forceinline__ u64 rng3(const u64* __restrict__ B, int cb, int wz) {
    u64 C = B[cb | wz], P = B[cb | ((wz + 3) & 3)], Nw = B[cb | ((wz + 1) & 3)];
    u64 d1 = (C << 1) | (P >> 63);
    u64 u1 = (C >> 1) | (Nw << 63);
    return C & d1 & u1;
}

__global__ void __launch_bounds__(256) solvent_bits_kernel(
    const u64* __restrict__ occ_bits, const u64* __restrict__ p_bits,
    u64* __restrict__ sol_bits)
{
    int w = blockIdx.x * 256 + threadIdx.x;
    int wz = w & 3, col = w >> 2;
    int y = col & 255, x = col >> 8;

    u64 ero = rng5(occ_bits, CB(x, y), wz);               // r2=0
    ero &= rng5(occ_bits, CB(x + 1, y), wz);              // r2=1
    ero &= rng5(occ_bits, CB(x - 1, y), wz);
    ero &= rng5(occ_bits, CB(x, y + 1), wz);
    ero &= rng5(occ_bits, CB(x, y - 1), wz);
    ero &= rng3(occ_bits, CB(x + 1, y + 1), wz);          // r2=2
    ero &= rng3(occ_bits, CB(x + 1, y - 1), wz);
    ero &= rng3(occ_bits, CB(x - 1, y + 1), wz);
    ero &= rng3(occ_bits, CB(x - 1, y - 1), wz);
    ero &= rng3(occ_bits, CB(x + 2, y), wz);              // r2=4
    ero &= rng3(occ_bits, CB(x - 2, y), wz);
    ero &= rng3(occ_bits, CB(x, y + 2), wz);
    ero &= rng3(occ_bits, CB(x, y - 2), wz);
    ero &= occ_bits[CB(x + 1, y + 2) | wz];               // r2=5: dz=0 only
    ero &= occ_bits[CB(x + 1, y - 2) | wz];
    ero &= occ_bits[CB(x - 1, y + 2) | wz];
    ero &= occ_bits[CB(x - 1, y - 2) | wz];
    ero &= occ_bits[CB(x + 2, y + 1) | wz];
    ero &= occ_bits[CB(x + 2, y - 1) | wz];
    ero &= occ_bits[CB(x - 2, y + 1) | wz];
    ero &= occ_bits[CB(x - 2, y - 1) | wz];

    u64 occw = occ_bits[w];
    u64 pw = p_bits[w];
    sol_bits[w] = ~(pw | (occw & ero));   // solvent = ~pwb
}

// ---------------- Stage 3: 3x3x3 Gaussian from bits (CSA + byte-spread) ----
struct Tri { u64 m1, m0, p1; };
__device__ __forceinline__ Tri tri(const u64* __restrict__ B, int x, int y, int wz) {
    int cb = CB(x, y);
    u64 C = B[cb | wz], P = B[cb | ((wz + 3) & 3)], Nw = B[cb | ((wz + 1) & 3)];
    Tri t;
    t.m0 = C;
    t.m1 = (C << 1) | (P >> 63);   // b(z-1)
    t.p1 = (C >> 1) | (Nw << 63);  // b(z+1)
    return t;
}

__device__ __forceinline__ void csa(u64 a, u64 b, u64 c, u64& s, u64& cy) {
    u64 t = a ^ b;
    s = t ^ c;
    cy = (a & b) | (t & c);
}

__global__ void __launch_bounds__(256) gauss_bits_kernel(
    const u64* __restrict__ S, float* __restrict__ out,
    float W0, float W1, float W2, float W3)
{
    __shared__ float lutA[256];              // W0*g + W1*c1 + W2*c2 (exact fma chain)
    __shared__ float lds[256][33];           // output staging, conflict-free stride
    const int tid = threadIdx.x;
    {
        int g = tid & 1, c1v = (tid >> 1) & 7, c2v = (tid >> 4) & 15;
        float acc = g ? W0 : 0.0f;
        acc = fmaf(W1, (float)c1v, acc);
        acc = fmaf(W2, (float)c2v, acc);
        lutA[tid] = acc;
    }
    __syncthreads();

    const int w = blockIdx.x * 256 + tid;
    const int wz = w & 3, col = w >> 2;
    const int y = col & 255, x = col >> 8;

    Tri cc = tri(S, x, y, wz);
    Tri e0 = tri(S, x + 1, y, wz), e1 = tri(S, x - 1, y, wz);
    Tri e2 = tri(S, x, y + 1, wz), e3 = tri(S, x, y - 1, wz);
    Tri d0 = tri(S, x + 1, y + 1, wz), d1 = tri(S, x + 1, y - 1, wz);
    Tri d2 = tri(S, x - 1, y + 1, wz), d3 = tri(S, x - 1, y - 1, wz);

    // ---- c1: 6 face/z-neighbors -> 3 counter planes --------------------
    u64 sa, ca, sb, cb2;
    csa(cc.m1, cc.p1, e0.m0, sa, ca);
    csa(e1.m0, e2.m0, e3.m0, sb, cb2);
    u64 c1b0 = sa ^ sb; u64 h = sa & sb;
    u64 c1b1, c1b2;
    csa(ca, cb2, h, c1b1, c1b2);

    // ---- c2: 12 edge-neighbors -> 4 counter planes ---------------------
    u64 s1, k1, s2, k2, s3, k3, s4, k4;
    csa(e0.m1, e0.p1, e1.m1, s1, k1);
    csa(e1.p1, e2.m1, e2.p1, s2, k2);
    csa(e3.m1, e3.p1, d0.m0, s3, k3);
    csa(d1.m0, d2.m0, d3.m0, s4, k4);
    u64 t5, kt;
    csa(s1, s2, s3, t5, kt);
    u64 c2b0 = t5 ^ s4; u64 h0 = t5 & s4;
    u64 u_, ku, v_, kv;
    csa(k1, k2, k3, u_, ku);
    csa(k4, kt, h0, v_, kv);
    u64 c2b1 = u_ ^ v_; u64 h1 = u_ & v_;
    u64 c2b2, c2b3;
    csa(ku, kv, h1, c2b2, c2b3);

    // ---- c3: 8 corner-neighbors -> 4 counter planes --------------------
    u64 p1s, p1c, p2s, p2c;
    csa(d0.m1, d0.p1, d1.m1, p1s, p1c);
    csa(d1.p1, d2.m1, d2.p1, p2s, p2c);
    u64 t3, kt3;
    csa(p1s, p2s, d3.m1, t3, kt3);
    u64 c3b0 = t3 ^ d3.p1; u64 h3 = t3 & d3.p1;
    u64 u3, ku3;
    csa(p1c, p2c, kt3, u3, ku3);
    u64 c3b1 = u3 ^ h3; u64 h4 = u3 & h3;
    u64 c3b2 = ku3 ^ h4, c3b3 = ku3 & h4;

    float* blk_out = out + (size_t)blockIdx.x * 256 * 64;

    #pragma unroll
    for (int hh = 0; hh < 2; ++hh) {
        const int sh = hh * 32;
        u32 pA[8] = { (u32)(cc.m0 >> sh), (u32)(c1b0 >> sh), (u32)(c1b1 >> sh),
                      (u32)(c1b2 >> sh), (u32)(c2b0 >> sh), (u32)(c2b1 >> sh),
                      (u32)(c2b2 >> sh), (u32)(c2b3 >> sh) };
        u32 pB[4] = { (u32)(c3b0 >> sh), (u32)(c3b1 >> sh),
                      (u32)(c3b2 >> sh), (u32)(c3b3 >> sh) };
        #pragma unroll
        for (int z0 = 0; z0 < 8; ++z0) {
            u32 accA = 0, accB = 0;
            #pragma unroll
            for (int j = 0; j < 8; ++j) accA |= ((pA[j] >> z0) & 0x01010101u) << j;
            #pragma unroll
            for (int j = 0; j < 4; ++j) accB |= ((pB[j] >> z0) & 0x01010101u) << j;
            #pragma unroll
            for (int b = 0; b < 4; ++b) {
                int idxA = (accA >> (8 * b)) & 255;
                int c3v  = (accB >> (8 * b)) & 15;
                float val = fmaf(W3, (float)c3v, lutA[idxA]);
                lds[tid][z0 + 8 * b] = val;
            }
        }
        __syncthreads();
        #pragma unroll
        for (int k = 0; k < 8; ++k) {
            int i = tid + k * 256;
            int wl = i >> 3;
            int zo = (i & 7) * 4;
            float4 v = make_float4(lds[wl][zo], lds[wl][zo + 1],
                                   lds[wl][zo + 2], lds[wl][zo + 3]);
            *(float4*)(blk_out + (size_t)wl * 64 + sh + zo) = v;
        }
        __syncthreads();
    }
}

extern "C" void kernel_launch(void* const* d_in, const int* in_sizes, int n_in,
                              void* d_out, int out_size, void* d_ws, size_t ws_size,
                              hipStream_t stream)
{
    const float* xyz = (const float*)d_in[0];
    const float* vdw = (const float*)d_in[1];
    float* out = (float*)d_out;

    u64* occ_bits = (u64*)d_ws;                  // 2 MB
    u64* p_bits   = occ_bits + NW;               // 2 MB
    u64* sol_bits = p_bits + NW;                 // 2 MB
    int* bin_cnt  = (int*)(sol_bits + NW);       // 16 KB
    int* bin_list = bin_cnt + NBIN * NBIN;       // 512 KB
    const int natoms = in_sizes[1];

    hipMemsetAsync(bin_cnt, 0, NBIN * NBIN * sizeof(int), stream);
    bin_fill_kernel<<<(natoms + 255) / 256, 256, 0, stream>>>(
        xyz, natoms, bin_cnt, bin_list);
    gather_splat_kernel<<<256, 256, 0, stream>>>(
        xyz, vdw, bin_cnt, bin_list, occ_bits, p_bits);
    solvent_bits_kernel<<<NW / 256, 256, 0, stream>>>(occ_bits, p_bits, sol_bits);

    // Gaussian weights in f64 like the reference, cast to f32
    double spacing = 100.0 / 256.0;
    double sigma = 1.1 / spacing / 4.0;
    double a = exp(-1.0 / (2.0 * sigma * sigma));
    double ssum = 2.0 * a + 1.0;
    double an = a / ssum, bn = 1.0 / ssum;       // normalized 1D taps; k3 sum == 1
    float W0 = (float)(bn * bn * bn);
    float W1 = (float)(an * bn * bn);
    float W2 = (float)(an * an * bn);
    float W3 = (float)(an * an * an);

    gauss_bits_kernel<<<NW / 256, 256, 0, stream>>>(sol_bits, out, W0, W1, W2, W3);
}

// Round 7
// 113.143 us; speedup vs baseline: 1.1925x; 1.1925x over previous
//
#include <hip/hip_runtime.h>
#include <math.h>

#define NG 256
#define NG3 (NG*NG*NG)
#define NW (NG3/64)          // 262144 u64 words, z-packed

typedef unsigned long long u64;
typedef unsigned int u32;

constexpr float SPACING_F = 0.390625f;   // 100/256, exact
constexpr int KH = 8;
constexpr int KD = 17;
constexpr int NPAIR = KD * KD;           // 289 (dx,dy) pairs per atom

// word layout: word = ((x<<8|y)<<2)|wz ; bit i = voxel z = wz*64+i
#define CB(x, y) (((((x) & 255) << 8) | ((y) & 255)) << 2)

// ------------- Stage 1: splat atoms straight into z-packed bitmasks --------
// (R4 version — scatter with global atomicOr; measured faster than gather)
__global__ void __launch_bounds__(256) splat_bits_kernel(
    const float* __restrict__ xyz, const float* __restrict__ vdw,
    u64* __restrict__ occ_bits, u64* __restrict__ p_bits, int natoms)
{
    int t = blockIdx.x * 256 + threadIdx.x;
    if (t >= natoms * NPAIR) return;
    int atom = t / NPAIR;
    int pr = t - atom * NPAIR;
    int dx = pr / KD - KH;
    int dy = pr - (pr / KD) * KD - KH;

    const float ax = xyz[atom * 3 + 0];
    const float ay = xyz[atom * 3 + 1];
    const float az = xyz[atom * 3 + 2];
    const float vr = vdw[atom];
    const float br = __fadd_rn(vr, 1.1f);
    const int bx = (int)floorf(__fdiv_rn(ax, SPACING_F));
    const int by = (int)floorf(__fdiv_rn(ay, SPACING_F));
    const int bz = (int)floorf(__fdiv_rn(az, SPACING_F));

    const int cx = bx + dx, cy = by + dy;
    float ex = __fsub_rn(__fmul_rn((float)cx, SPACING_F), ax);
    float ey = __fsub_rn(__fmul_rn((float)cy, SPACING_F), ay);
    float rxy2 = __fadd_rn(__fmul_rn(ex, ex), __fmul_rn(ey, ey));
    // Early-out: RN add of nonneg is monotone and fsqrt_rn(fmul_rn(br,br))==br
    if (rxy2 >= __fmul_rn(br, br)) return;

    u32 mo = 0, mp = 0;
    #pragma unroll
    for (int k = 0; k < KD; ++k) {
        int cz = bz + k - KH;
        float ez = __fsub_rn(__fmul_rn((float)cz, SPACING_F), az);
        float s = __fadd_rn(rxy2, __fmul_rn(ez, ez));   // same assoc as ref
        float d = __fsqrt_rn(s);
        mo |= (d < br) ? (1u << k) : 0u;
        mp |= (d < vr) ? (1u << k) : 0u;
    }
    if (!mo) return;

    const int cb = CB(cx, cy);
    const int zA = (bz - KH) & 255;       // z of mask bit 0 (wrapped)
    const int wa = zA >> 6;
    const int off = zA & 63;

    u64 lo = (u64)mo << off;
    u64 hi = off ? ((u64)mo >> (64 - off)) : 0ULL;
    if (lo) atomicOr(&occ_bits[cb | wa], lo);
    if (hi) atomicOr(&occ_bits[cb | ((wa + 1) & 3)], hi);
    if (mp) {
        u64 plo = (u64)mp << off;
        u64 phi = off ? ((u64)mp >> (64 - off)) : 0ULL;
        if (plo) atomicOr(&p_bits[cb | wa], plo);
        if (phi) atomicOr(&p_bits[cb | ((wa + 1) & 3)], phi);
    }
}

// ---------------- Stage 2+3 fused: solvent (LDS) + gauss -------------------
// Block = 8x8 columns (x0..x0+7, y0..y0+7) * 4 wz = 256 output words.
// occ halo tile: 14x14 cols; solvent tile: 10x10 cols.
// LDS occ tile layout: occT[(ox*14+oy)*4 + wz]
#define LCB(ox, oy) ((((ox) * 14) + (oy)) * 4)
#define SCB(sx, sy) ((((sx) * 10) + (sy)) * 4)

union SMem {
    u64 occT[784];           // 6272 B  (phases 1-2)
    float stage[256][33];    // 33792 B (phase 3 drain staging)
};

__device__ __forceinline__ u64 lrng5(const u64* T, int cb, int wz) {
    u64 C = T[cb | wz], P = T[cb | ((wz + 3) & 3)], Nw = T[cb | ((wz + 1) & 3)];
    u64 d1 = (C << 1) | (P >> 63), d2 = (C << 2) | (P >> 62);
    u64 u1 = (C >> 1) | (Nw << 63), u2 = (C >> 2) | (Nw << 62);
    return C & d1 & d2 & u1 & u2;
}
__device__ __forceinline__ u64 lrng3(const u64* T, int cb, int wz) {
    u64 C = T[cb | wz], P = T[cb | ((wz + 3) & 3)], Nw = T[cb | ((wz + 1) & 3)];
    u64 d1 = (C << 1) | (P >> 63);
    u64 u1 = (C >> 1) | (Nw << 63);
    return C & d1 & u1;
}

struct Tri { u64 m1, m0, p1; };
__device__ __forceinline__ Tri triL(const u64* T, int cb, int wz) {
    u64 C = T[cb | wz], P = T[cb | ((wz + 3) & 3)], Nw = T[cb | ((wz + 1) & 3)];
    Tri t;
    t.m0 = C;
    t.m1 = (C << 1) | (P >> 63);   // b(z-1)
    t.p1 = (C >> 1) | (Nw << 63);  // b(z+1)
    return t;
}

__device__ __forceinline__ void csa(u64 a, u64 b, u64 c, u64& s, u64& cy) {
    u64 t = a ^ b;
    s = t ^ c;
    cy = (a & b) | (t & c);
}

__global__ void __launch_bounds__(256) solv_gauss_kernel(
    const u64* __restrict__ occ_bits, const u64* __restrict__ p_bits,
    float* __restrict__ out, float W0, float W1, float W2, float W3)
{
    __shared__ SMem sm;
    __shared__ u64 solT[400];
    __shared__ float lutA[256];

    const int tid = threadIdx.x;
    const int bx = blockIdx.x & 31, by = blockIdx.x >> 5;
    const int x0 = bx * 8, y0 = by * 8;

    // ---- phase 1: load occ halo tile (14x14x4 words), init LUT ----
    for (int i = tid; i < 784; i += 256) {
        int owz = i & 3; int c = i >> 2;        // c = ox*14+oy
        int oy = c % 14, ox = c / 14;
        sm.occT[i] = occ_bits[CB(x0 - 3 + ox, y0 - 3 + oy) | owz];
    }
    {
        int g = tid & 1, c1v = (tid >> 1) & 7, c2v = (tid >> 4) & 15;
        float acc = g ? W0 : 0.0f;
        acc = fmaf(W1, (float)c1v, acc);
        acc = fmaf(W2, (float)c2v, acc);
        lutA[tid] = acc;
    }
    __syncthreads();

    // ---- phase 2: solvent for 10x10x4 halo region into solT ----
    for (int i = tid; i < 400; i += 256) {
        int swz = i & 3; int c = i >> 2;        // c = sx*10+sy
        int sy = c % 10, sx = c / 10;
        int ox = sx + 2, oy = sy + 2;
        const u64* T = sm.occT;
        u64 ero = lrng5(T, LCB(ox, oy), swz);                 // r2=0
        ero &= lrng5(T, LCB(ox + 1, oy), swz);                // r2=1
        ero &= lrng5(T, LCB(ox - 1, oy), swz);
        ero &= lrng5(T, LCB(ox, oy + 1), swz);
        ero &= lrng5(T, LCB(ox, oy - 1), swz);
        ero &= lrng3(T, LCB(ox + 1, oy + 1), swz);            // r2=2
        ero &= lrng3(T, LCB(ox + 1, oy - 1), swz);
        ero &= lrng3(T, LCB(ox - 1, oy + 1), swz);
        ero &= lrng3(T, LCB(ox - 1, oy - 1), swz);
        ero &= lrng3(T, LCB(ox + 2, oy), swz);                // r2=4
        ero &= lrng3(T, LCB(ox - 2, oy), swz);
        ero &= lrng3(T, LCB(ox, oy + 2), swz);
        ero &= lrng3(T, LCB(ox, oy - 2), swz);
        ero &= T[LCB(ox + 1, oy + 2) | swz];                  // r2=5: dz=0 only
        ero &= T[LCB(ox + 1, oy - 2) | swz];
        ero &= T[LCB(ox - 1, oy + 2) | swz];
        ero &= T[LCB(ox - 1, oy - 2) | swz];
        ero &= T[LCB(ox + 2, oy + 1) | swz];
        ero &= T[LCB(ox + 2, oy - 1) | swz];
        ero &= T[LCB(ox - 2, oy + 1) | swz];
        ero &= T[LCB(ox - 2, oy - 1) | swz];

        u64 C = T[LCB(ox, oy) | swz];
        u64 pw = p_bits[CB(x0 - 1 + sx, y0 - 1 + sy) | swz];
        solT[i] = ~(pw | (C & ero));            // solvent = ~pwb
    }
    __syncthreads();      // solT ready; occT dead -> sm.stage reusable

    // ---- phase 3: 3x3x3 gauss from solT, CSA counters + byte-spread ----
    const int gwz = tid & 3;
    const int gc = tid >> 2;          // gx*8+gy
    const int gy = gc & 7, gx = gc >> 3;
    const int sx = gx + 1, sy = gy + 1;

    Tri cc = triL(solT, SCB(sx, sy), gwz);
    Tri e0 = triL(solT, SCB(sx + 1, sy), gwz), e1 = triL(solT, SCB(sx - 1, sy), gwz);
    Tri e2 = triL(solT, SCB(sx, sy + 1), gwz), e3 = triL(solT, SCB(sx, sy - 1), gwz);
    Tri d0 = triL(solT, SCB(sx + 1, sy + 1), gwz), d1 = triL(solT, SCB(sx + 1, sy - 1), gwz);
    Tri d2 = triL(solT, SCB(sx - 1, sy + 1), gwz), d3 = triL(solT, SCB(sx - 1, sy - 1), gwz);

    // c1: 6 face/z-neighbors -> 3 counter planes
    u64 sa, ca, sb, cb2;
    csa(cc.m1, cc.p1, e0.m0, sa, ca);
    csa(e1.m0, e2.m0, e3.m0, sb, cb2);
    u64 c1b0 = sa ^ sb; u64 h = sa & sb;
    u64 c1b1, c1b2;
    csa(ca, cb2, h, c1b1, c1b2);

    // c2: 12 edge-neighbors -> 4 counter planes
    u64 s1, k1, s2, k2, s3, k3, s4, k4;
    csa(e0.m1, e0.p1, e1.m1, s1, k1);
    csa(e1.p1, e2.m1, e2.p1, s2, k2);
    csa(e3.m1, e3.p1, d0.m0, s3, k3);
    csa(d1.m0, d2.m0, d3.m0, s4, k4);
    u64 t5, kt;
    csa(s1, s2, s3, t5, kt);
    u64 c2b0 = t5 ^ s4; u64 h0 = t5 & s4;
    u64 u_, ku, v_, kv;
    csa(k1, k2, k3, u_, ku);
    csa(k4, kt, h0, v_, kv);
    u64 c2b1 = u_ ^ v_; u64 h1 = u_ & v_;
    u64 c2b2, c2b3;
    csa(ku, kv, h1, c2b2, c2b3);

    // c3: 8 corner-neighbors -> 4 counter planes
    u64 p1s, p1c, p2s, p2c;
    csa(d0.m1, d0.p1, d1.m1, p1s, p1c);
    csa(d1.p1, d2.m1, d2.p1, p2s, p2c);
    u64 t3, kt3;
    csa(p1s, p2s, d3.m1, t3, kt3);
    u64 c3b0 = t3 ^ d3.p1; u64 h3 = t3 & d3.p1;
    u64 u3, ku3;
    csa(p1c, p2c, kt3, u3, ku3);
    u64 c3b1 = u3 ^ h3; u64 h4 = u3 & h3;
    u64 c3b2 = ku3 ^ h4, c3b3 = ku3 & h4;

    #pragma unroll
    for (int hh = 0; hh < 2; ++hh) {
        const int sh = hh * 32;
        u32 pA[8] = { (u32)(cc.m0 >> sh), (u32)(c1b0 >> sh), (u32)(c1b1 >> sh),
                      (u32)(c1b2 >> sh), (u32)(c2b0 >> sh), (u32)(c2b1 >> sh),
                      (u32)(c2b2 >> sh), (u32)(c2b3 >> sh) };
        u32 pB[4] = { (u32)(c3b0 >> sh), (u32)(c3b1 >> sh),
                      (u32)(c3b2 >> sh), (u32)(c3b3 >> sh) };
        #pragma unroll
        for (int z0 = 0; z0 < 8; ++z0) {
            u32 accA = 0, accB = 0;
            #pragma unroll
            for (int j = 0; j < 8; ++j) accA |= ((pA[j] >> z0) & 0x01010101u) << j;
            #pragma unroll
            for (int j = 0; j < 4; ++j) accB |= ((pB[j] >> z0) & 0x01010101u) << j;
            #pragma unroll
            for (int b = 0; b < 4; ++b) {
                int idxA = (accA >> (8 * b)) & 255;
                int c3v  = (accB >> (8 * b)) & 15;
                float val = fmaf(W3, (float)c3v, lutA[idxA]);
                sm.stage[tid][z0 + 8 * b] = val;
            }
        }
        __syncthreads();
        // drain: 8 lanes cover one word's 32-float half = one full 128B line
        #pragma unroll
        for (int k = 0; k < 8; ++k) {
            int i = tid + k * 256;            // float4 id in [0,2048)
            int wl = i >> 3;                  // local word 0..255
            int zo = (i & 7) * 4;
            int ggx = wl >> 5, ggy = (wl >> 2) & 7, ggwz = wl & 3;
            size_t base = ((size_t)(((x0 + ggx) << 10) + (y0 + ggy) * 4 + ggwz)) * 64;
            float4 v = make_float4(sm.stage[wl][zo], sm.stage[wl][zo + 1],
                                   sm.stage[wl][zo + 2], sm.stage[wl][zo + 3]);
            *(float4*)(out + base + sh + zo) = v;
        }
        __syncthreads();
    }
}

extern "C" void kernel_launch(void* const* d_in, const int* in_sizes, int n_in,
                              void* d_out, int out_size, void* d_ws, size_t ws_size,
                              hipStream_t stream)
{
    const float* xyz = (const float*)d_in[0];
    const float* vdw = (const float*)d_in[1];
    float* out = (float*)d_out;

    u64* occ_bits = (u64*)d_ws;          // 2 MB
    u64* p_bits   = occ_bits + NW;       // 2 MB
    const int natoms = in_sizes[1];

    hipMemsetAsync(occ_bits, 0, 2 * NW * sizeof(u64), stream);

    int nthreads = natoms * NPAIR;
    splat_bits_kernel<<<(nthreads + 255) / 256, 256, 0, stream>>>(
        xyz, vdw, occ_bits, p_bits, natoms);

    // Gaussian weights in f64 like the reference, cast to f32
    double spacing = 100.0 / 256.0;
    double sigma = 1.1 / spacing / 4.0;
    double a = exp(-1.0 / (2.0 * sigma * sigma));
    double ssum = 2.0 * a + 1.0;
    double an = a / ssum, bn = 1.0 / ssum;   // normalized 1D taps; k3 sum == 1
    float W0 = (float)(bn * bn * bn);
    float W1 = (float)(an * bn * bn);
    float W2 = (float)(an * an * bn);
    float W3 = (float)(an * an * an);

    solv_gauss_kernel<<<1024, 256, 0, stream>>>(
        occ_bits, p_bits, out, W0, W1, W2, W3);
}